// Round 17
// baseline (120.201 us; speedup 1.0000x reference)
//
#include <hip/hip_runtime.h>
#include <math.h>

#define CC    64
#define BATCH 2048
#define EPS   1e-5f
#define SLOPE 0.01f

// ws layout (float indices):
#define WS_SUMR  0        // 32 replicas x 128 (c,o)
#define WS_SQR   4096     // 32 replicas x 128
#define WS_A     8192     // 128
#define WS_B     8320     // 128
#define WS_WF    8448     // 64*128 folded weights
#define WS_WB    16640    // 64 per-channel bias contribution
#define WS_LOGIT 16704    // 2048 (fallback path only)
#define WS_POOL  18944    // 2048*64*128 uint (bf16 mx | bf16 mn), 16B-aligned
#define WS_NEEDED_BYTES ((size_t)(WS_POOL + (size_t)BATCH * CC * 128) * 4)

__device__ inline unsigned bf16rne(float x) {
    unsigned u = __float_as_uint(x);
    return (u + 0x7fffu + ((u >> 16) & 1u)) >> 16;
}
__device__ inline float blo(unsigned u) { return __uint_as_float(u << 16); }
__device__ inline float bhi(unsigned u) { return __uint_as_float(u & 0xffff0000u); }

// guaranteed packed f32 FMA: acc = a*b + acc (VOP3P v_pk_fma_f32, CDNA4)
__device__ inline void pkfma(float2& acc, float2 a, float2 b) {
    asm("v_pk_fma_f32 %0, %1, %2, %0" : "+v"(acc) : "v"(a), "v"(b));
}

// ---------------- Pass 1: conv + batch stats (+ pooled bf16 max/min store) ----------------
// One 64-thread block = one wave = 2 images (b,c0),(b,c0+1).
// LDS holds inputs as bf16: ldsh[src][row'*24 + col], row' = img*19 + row (38 rows, stride
// 24 ushorts = 48 B so every window base is 16B-aligned). Halves LDS read bytes.
// Lane t: img=t>>5, o=(t>>4)&1, p=t&15, pi=p>>1, pjp=p&1
//   -> 4 pooled cells (pi, 4pjp..4pjp+3): conv rows 2pi..2pi+1, conv cols 8pjp..8pjp+7,
//      input window rows 2pi..2pi+3, cols 8pjp..8pjp+9 (5 u32 = uint4 + u32, aligned).
template<bool STORE>
__global__ __launch_bounds__(64, 4) void pass1_kernel(
    const float* __restrict__ x1, const float* __restrict__ x2,
    const float* __restrict__ conv_w, const float* __restrict__ conv_b,
    float* __restrict__ ws)
{
    __shared__ __align__(16) unsigned short ldsh[2][912];   // [src][row'*24+col]

    int blk = blockIdx.x;            // b*32 + cpair
    int b  = blk >> 5;
    int c0 = (blk & 31) * 2;
    int t  = threadIdx.x;            // 0..63

    // staging: 361 float2 per source; ushort idx = e + 5*row (row = e/19 via magic)
    const float2* g1 = (const float2*)(x1 + ((size_t)b * 64 + c0) * 361);
    const float2* g2 = (const float2*)(x2 + ((size_t)b * 64 + c0) * 361);
    #pragma unroll
    for (int sl = 0; sl < 6; sl++) {
        int g = t + 64 * sl;
        if (sl < 5 || g < 361) {
            float2 v1 = g1[g];
            float2 v2 = g2[g];
            unsigned e  = 2u * g;
            unsigned r0 = (e * 110377u) >> 21;          // e/19 (exact for e<=721)
            unsigned r1 = ((e + 1u) * 110377u) >> 21;
            int i0 = e + 5 * r0;
            int i1 = e + 1 + 5 * r1;
            ldsh[0][i0] = (unsigned short)bf16rne(v1.x);
            ldsh[0][i1] = (unsigned short)bf16rne(v1.y);
            ldsh[1][i0] = (unsigned short)bf16rne(v2.x);
            ldsh[1][i1] = (unsigned short)bf16rne(v2.y);
        }
    }

    int img = t >> 5;
    int u   = t & 31;
    int o   = u >> 4;
    int p   = u & 15;
    int pi  = p >> 1;
    int pjp = p & 1;
    int c   = c0 + img;

    // weights as {w,w} pairs
    const float2* wp2 = (const float2*)(conv_w + (size_t)(c * 2 + o) * 18);
    float2 wgt[18];
    #pragma unroll
    for (int j = 0; j < 9; j++) {
        float2 pr = wp2[j];
        wgt[2 * j]     = make_float2(pr.x, pr.x);
        wgt[2 * j + 1] = make_float2(pr.y, pr.y);
    }
    float cbv = conv_b[c * 2 + o];

    __syncthreads();

    // A[di][k] = conv outputs {row 2pi+di, cols 8pjp+2k, 8pjp+2k+1} (cell k of 4)
    float2 A[2][4];
    #pragma unroll
    for (int di = 0; di < 2; di++)
        #pragma unroll
        for (int k = 0; k < 4; k++)
            A[di][k] = make_float2(cbv, cbv);

    #pragma unroll
    for (int ic = 0; ic < 2; ic++) {
        const float2* wic = &wgt[ic * 9];
        #pragma unroll
        for (int r = 0; r < 4; r++) {
            const unsigned short* rowp =
                &ldsh[ic][(img * 19 + 2 * pi + r) * 24 + 8 * pjp];   // 16B-aligned
            uint4 U = *(const uint4*)rowp;            // cols 0..7 (bf16 pairs)
            unsigned T = *(const unsigned*)(rowp + 8); // cols 8,9
            float x0 = blo(U.x), x1v = bhi(U.x);
            float x2v = blo(U.y), x3 = bhi(U.y);
            float x4 = blo(U.z), x5v = bhi(U.z);
            float x6 = blo(U.w), x7 = bhi(U.w);
            float x8 = blo(T),   x9 = bhi(T);
            float2 P[9];
            P[0] = make_float2(x0, x1v);
            P[1] = make_float2(x1v, x2v);
            P[2] = make_float2(x2v, x3);
            P[3] = make_float2(x3, x4);
            P[4] = make_float2(x4, x5v);
            P[5] = make_float2(x5v, x6);
            P[6] = make_float2(x6, x7);
            P[7] = make_float2(x7, x8);
            P[8] = make_float2(x8, x9);
            #pragma unroll
            for (int di = 0; di < 2; di++) {
                int ki = r - di;
                if (ki < 0 || ki > 2) continue;
                #pragma unroll
                for (int k = 0; k < 4; k++)
                    #pragma unroll
                    for (int kj = 0; kj < 3; kj++)
                        pkfma(A[di][k], P[2 * k + kj], wic[3 * ki + kj]);
            }
        }
    }

    // stats + pooled max/min (cell k: A[0][k], A[1][k])
    const float2 one2 = make_float2(1.f, 1.f);
    float2 sp = make_float2(0.f, 0.f), q2 = make_float2(0.f, 0.f);
    #pragma unroll
    for (int di = 0; di < 2; di++)
        #pragma unroll
        for (int k = 0; k < 4; k++) {
            pkfma(sp, A[di][k], one2);
            pkfma(q2, A[di][k], A[di][k]);
        }
    float s = sp.x + sp.y;
    float q = q2.x + q2.y;

    if (STORE) {
        unsigned pk[4];
        #pragma unroll
        for (int k = 0; k < 4; k++) {
            float mx = fmaxf(fmaxf(A[0][k].x, A[0][k].y), fmaxf(A[1][k].x, A[1][k].y));
            float mn = fminf(fminf(A[0][k].x, A[0][k].y), fminf(A[1][k].x, A[1][k].y));
            pk[k] = (bf16rne(mx) << 16) | bf16rne(mn);
        }
        uint4* pool4 = (uint4*)(ws + WS_POOL);
        pool4[((size_t)(b * 64 + c)) * 32 + o * 16 + pi * 2 + pjp] =
            make_uint4(pk[0], pk[1], pk[2], pk[3]);
    }

    // border outputs (stats only), 33 per (img,o): 2 reps + (15,16) on p==0.
    // Reads cols as u32 bf16-pairs with branchless parity select.
    #pragma unroll
    for (int rep = 0; rep < 2; rep++) {
        int bidx = p + 16 * rep;
        int bi = bidx < 17 ? 16 : bidx - 17;
        int bj = bidx < 17 ? bidx : 16;
        int ba = bj & ~1;
        int odd = bj & 1;
        float accb = cbv;
        #pragma unroll
        for (int ic = 0; ic < 2; ic++)
            #pragma unroll
            for (int ki = 0; ki < 3; ki++) {
                const unsigned* pp =
                    (const unsigned*)&ldsh[ic][(img * 19 + bi + ki) * 24 + ba];
                unsigned Va = pp[0], Vb = pp[1];
                float a0 = blo(Va), a1 = bhi(Va), b0 = blo(Vb), b1 = bhi(Vb);
                float f0 = odd ? a1 : a0;
                float f1 = odd ? b0 : a1;
                float f2 = odd ? b1 : b0;
                accb = fmaf(f0, wgt[ic * 9 + ki * 3 + 0].x, accb);
                accb = fmaf(f1, wgt[ic * 9 + ki * 3 + 1].x, accb);
                accb = fmaf(f2, wgt[ic * 9 + ki * 3 + 2].x, accb);
            }
        s += accb; q = fmaf(accb, accb, q);
    }
    if (p == 0) {   // (15,16): cols 16,17,18 -> ba=16 even
        float accb = cbv;
        #pragma unroll
        for (int ic = 0; ic < 2; ic++)
            #pragma unroll
            for (int ki = 0; ki < 3; ki++) {
                const unsigned* pp =
                    (const unsigned*)&ldsh[ic][(img * 19 + 15 + ki) * 24 + 16];
                unsigned Va = pp[0], Vb = pp[1];
                accb = fmaf(blo(Va), wgt[ic * 9 + ki * 3 + 0].x, accb);
                accb = fmaf(bhi(Va), wgt[ic * 9 + ki * 3 + 1].x, accb);
                accb = fmaf(blo(Vb), wgt[ic * 9 + ki * 3 + 2].x, accb);
            }
        s += accb; q = fmaf(accb, accb, q);
    }

    // reduce within each 16-lane (img,o) group
    #pragma unroll
    for (int off = 8; off > 0; off >>= 1) {
        s += __shfl_down(s, off, 16);
        q += __shfl_down(q, off, 16);
    }
    if (p == 0) {
        int rep = b & 31;
        atomicAdd(&ws[WS_SUMR + rep * 128 + c * 2 + o], s);
        atomicAdd(&ws[WS_SQR  + rep * 128 + c * 2 + o], q);
    }
}

// ---------------- Prep: replica-sum stats, BN scale/shift, folded fc weights ----------------
__global__ __launch_bounds__(128) void prep_kernel(
    const float* __restrict__ bn_g, const float* __restrict__ bn_b,
    const float* __restrict__ fc1_w, const float* __restrict__ fc1_b,
    const float* __restrict__ fc2_w, const float* __restrict__ fc2_b,
    const float* __restrict__ w_out,
    float* __restrict__ ws)
{
    int c = blockIdx.x;
    int f = threadIdx.x;

    float wsum = 0.f;
    #pragma unroll
    for (int h = 0; h < 8; h++)
        wsum += fc2_w[c * 8 + h] * fc1_w[(c * 8 + h) * 128 + f];
    ws[WS_WF + c * 128 + f] = w_out[c] * wsum;

    if (f == 0) {
        float bsum = fc2_b[c];
        #pragma unroll
        for (int h = 0; h < 8; h++)
            bsum += fc2_w[c * 8 + h] * fc1_b[c * 8 + h];
        ws[WS_WB + c] = w_out[c] * bsum;
    }
    if (f < 2) {
        int idx = c * 2 + f;
        float s = 0.f, q = 0.f;
        for (int r = 0; r < 32; r++) {
            s += ws[WS_SUMR + r * 128 + idx];
            q += ws[WS_SQR  + r * 128 + idx];
        }
        const float N = 2048.0f * 289.0f;
        float mean = s / N;
        float var  = q / N - mean * mean;
        float inv  = rsqrtf(var + EPS);
        float A    = bn_g[idx] * inv;
        ws[WS_A + idx] = A;
        ws[WS_B + idx] = bn_b[idx] - mean * A;
    }
}

// ---------------- Pass 2: stream bf16 pool -> logits -> sigmoid ----------------
__global__ __launch_bounds__(256) void pass2_kernel(
    const float* __restrict__ ws, const float* __restrict__ b_out,
    float* __restrict__ out)
{
    __shared__ float red[4];
    int b = blockIdx.x;
    int t = threadIdx.x;
    const uint4* pool = (const uint4*)(ws + WS_POOL) + (size_t)b * 2048;

    float partial = (t < 64) ? ws[WS_WB + t] : 0.f;
    if (t == 0) partial += b_out[0];

    #pragma unroll
    for (int i = 0; i < 8; i++) {
        uint4 p = pool[t + i * 256];
        int k0 = (t + i * 256) * 4;
        float A  = ws[WS_A + (k0 >> 6)];
        float Bs = ws[WS_B + (k0 >> 6)];
        const float4 wf = *(const float4*)&ws[WS_WF + k0];
        unsigned uu[4] = { p.x, p.y, p.z, p.w };
        float wfv[4] = { wf.x, wf.y, wf.z, wf.w };
        #pragma unroll
        for (int j = 0; j < 4; j++) {
            float mx = __uint_as_float(uu[j] & 0xffff0000u);
            float mn = __uint_as_float(uu[j] << 16);
            float val = A > 0.f ? mx : mn;
            float v = fmaf(A, val, Bs);
            v = v > 0.f ? v : SLOPE * v;
            partial = fmaf(v, wfv[j], partial);
        }
    }

    #pragma unroll
    for (int off = 32; off > 0; off >>= 1)
        partial += __shfl_down(partial, off);
    if ((t & 63) == 0) red[t >> 6] = partial;
    __syncthreads();
    if (t == 0) {
        float lsum = red[0] + red[1] + red[2] + red[3];
        out[b] = 1.f / (1.f + expf(-lsum));
    }
}

// ---------------- Fallback path (small ws): recompute conv with BN applied ----------------
__global__ __launch_bounds__(128) void main_fb_kernel(
    const float* __restrict__ x1, const float* __restrict__ x2,
    const float* __restrict__ conv_w, const float* __restrict__ conv_b,
    float* __restrict__ ws)
{
    __shared__ float lds[2][19 * 20];
    __shared__ float red[2];

    int blk = blockIdx.x;
    int c = blk & 63;
    int b = blk >> 6;
    int t = threadIdx.x;

    const float* src1 = x1 + (size_t)blk * 361;
    const float* src2 = x2 + (size_t)blk * 361;
    for (int i = t; i < 361; i += 128) {
        int r = i / 19;
        int col = i - r * 19;
        lds[0][r * 20 + col] = src1[i];
        lds[1][r * 20 + col] = src2[i];
    }

    int o = t >> 6;
    int l = t & 63;
    int pi = l >> 3, pj = l & 7;

    const float* wcp = conv_w + c * 36 + o * 18;
    float w0[9], w1[9];
    #pragma unroll
    for (int k = 0; k < 9; k++) { w0[k] = wcp[k]; w1[k] = wcp[9 + k]; }
    float cbv = conv_b[c * 2 + o];
    float A   = ws[WS_A + c * 2 + o];
    float Bs  = ws[WS_B + c * 2 + o];
    float wf  = ws[WS_WF + c * 128 + t];

    __syncthreads();

    float xw[2][4][4];
    int base = (2 * pi) * 20 + 2 * pj;
    #pragma unroll
    for (int ic = 0; ic < 2; ic++)
        #pragma unroll
        for (int r = 0; r < 4; r++)
            #pragma unroll
            for (int cc = 0; cc < 4; cc++)
                xw[ic][r][cc] = lds[ic][base + r * 20 + cc];

    float m = -3.4e38f;
    #pragma unroll
    for (int di = 0; di < 2; di++)
        #pragma unroll
        for (int dj = 0; dj < 2; dj++) {
            float acc = cbv;
            #pragma unroll
            for (int ki = 0; ki < 3; ki++)
                #pragma unroll
                for (int kj = 0; kj < 3; kj++) {
                    acc = fmaf(xw[0][di + ki][dj + kj], w0[ki * 3 + kj], acc);
                    acc = fmaf(xw[1][di + ki][dj + kj], w1[ki * 3 + kj], acc);
                }
            float v = fmaf(A, acc, Bs);
            v = v > 0.f ? v : SLOPE * v;
            m = fmaxf(m, v);
        }

    float contrib = m * wf;
    #pragma unroll
    for (int off = 32; off > 0; off >>= 1)
        contrib += __shfl_down(contrib, off);
    if (l == 0) red[o] = contrib;
    __syncthreads();
    if (t == 0)
        atomicAdd(&ws[WS_LOGIT + b], red[0] + red[1]);
}

__global__ __launch_bounds__(256) void final_fb_kernel(
    const float* __restrict__ ws, const float* __restrict__ b_out,
    float* __restrict__ out)
{
    int b = blockIdx.x * blockDim.x + threadIdx.x;
    if (b >= BATCH) return;
    float bias = b_out[0];
    #pragma unroll
    for (int c = 0; c < CC; c++) bias += ws[WS_WB + c];
    float l = ws[WS_LOGIT + b] + bias;
    out[b] = 1.f / (1.f + expf(-l));
}

extern "C" void kernel_launch(void* const* d_in, const int* in_sizes, int n_in,
                              void* d_out, int out_size, void* d_ws, size_t ws_size,
                              hipStream_t stream) {
    const float* x1     = (const float*)d_in[0];
    const float* x2     = (const float*)d_in[1];
    const float* conv_w = (const float*)d_in[2];
    const float* conv_b = (const float*)d_in[3];
    const float* bn_g   = (const float*)d_in[4];
    const float* bn_b   = (const float*)d_in[5];
    const float* fc1_w  = (const float*)d_in[6];
    const float* fc1_b  = (const float*)d_in[7];
    const float* fc2_w  = (const float*)d_in[8];
    const float* fc2_b  = (const float*)d_in[9];
    const float* w_out  = (const float*)d_in[10];
    const float* b_out  = (const float*)d_in[11];
    float* ws  = (float*)d_ws;
    float* out = (float*)d_out;

    dim3 big(BATCH * 32);            // 1 wave per block, 2 images per wave
    bool pool_path = ws_size >= WS_NEEDED_BYTES;

    if (pool_path) {
        hipMemsetAsync(d_ws, 0, 8192 * sizeof(float), stream);   // stats replicas
        pass1_kernel<true><<<big, 64, 0, stream>>>(x1, x2, conv_w, conv_b, ws);
        prep_kernel<<<CC, 128, 0, stream>>>(bn_g, bn_b, fc1_w, fc1_b, fc2_w, fc2_b, w_out, ws);
        pass2_kernel<<<BATCH, 256, 0, stream>>>(ws, b_out, out);
    } else {
        hipMemsetAsync(d_ws, 0, 18752 * sizeof(float), stream);  // stats + logits
        pass1_kernel<false><<<big, 64, 0, stream>>>(x1, x2, conv_w, conv_b, ws);
        prep_kernel<<<CC, 128, 0, stream>>>(bn_g, bn_b, fc1_w, fc1_b, fc2_w, fc2_b, w_out, ws);
        main_fb_kernel<<<dim3(BATCH * CC), 128, 0, stream>>>(x1, x2, conv_w, conv_b, ws);
        final_fb_kernel<<<(BATCH + 255) / 256, 256, 0, stream>>>(ws, b_out, out);
    }
}